// Round 16
// baseline (63.274 us; speedup 1.0000x reference)
//
#include <hip/hip_runtime.h>

// B=256, F=32, N=16, D=512
//   sims[b,f,c,n] = relu(face[b,f]·ner[c,n])      (8192 x 4096 NT GEMM, K=512)
//   S_all[b,f]    = sum_{c,n} masked(sims)        (masked: ==1.0 -> 0)
//   pos[b,f]      = sum_n sims[b,f,b,n]           (unmasked diagonal)
//   diag_m[b,f]   = sum_n masked(sims[b,f,b,n])
//   loss = sum(relu((S_all-diag_m)/255 - pos + 0.2) * face_mask) / 256
//
// Round 16: r15 consolidated pipeline, GEMM K-loop swapped for the CLEAN
// 3-buffer ring (r7 logic minus the FETCH-doubling XCD swizzle confound):
// STAGE(t+2) -> KBODY(t) -> counted vmcnt(4) -> one s_barrier per K-tile.
// Natural block order. Isolates "staging lead hides L2 latency" as the
// single variable vs r15's drain-per-tile loop.

#define DIM_D 512
#define M_TOT 8192
#define N_TOT 4096

typedef __attribute__((ext_vector_type(8))) short short8v;
typedef __attribute__((ext_vector_type(4))) float f32x4;

__device__ __forceinline__ unsigned short f2bf(float f) {
  unsigned int u = __builtin_bit_cast(unsigned int, f);
  u += 0x7fffu + ((u >> 16) & 1u);
  return (unsigned short)(u >> 16);
}

// ---------------------------------------------------------------------------
// Merged cvt: face+ner fp32 -> bf16, face_mask, and S_all zeroing.
// ---------------------------------------------------------------------------
__global__ __launch_bounds__(256) void cvt_all(
    const float* __restrict__ face, const float* __restrict__ ner,
    unsigned short* __restrict__ face_bf, unsigned short* __restrict__ ner_bf,
    float* __restrict__ mask, float* __restrict__ S_all) {
  if (blockIdx.x < 8) {  // 8 blocks x 256 thr x 4 floats = 8192 = S_all
    const int i = blockIdx.x * 1024 + threadIdx.x * 4;
    *(float4*)(S_all + i) = (float4){0.f, 0.f, 0.f, 0.f};
  }
  const int gw = blockIdx.x * 4 + (threadIdx.x >> 6);
  const int lane = threadIdx.x & 63;
  const bool isFace = gw < M_TOT;
  const int row = isFace ? gw : gw - M_TOT;
  const float* src = (isFace ? face : ner) + (size_t)row * DIM_D;
  unsigned short* dst = (isFace ? face_bf : ner_bf) + (size_t)row * DIM_D;

  const float4 f0 = ((const float4*)src)[lane * 2];
  const float4 f1 = ((const float4*)src)[lane * 2 + 1];
  short8v o;
  o[0] = (short)f2bf(f0.x); o[1] = (short)f2bf(f0.y);
  o[2] = (short)f2bf(f0.z); o[3] = (short)f2bf(f0.w);
  o[4] = (short)f2bf(f1.x); o[5] = (short)f2bf(f1.y);
  o[6] = (short)f2bf(f1.z); o[7] = (short)f2bf(f1.w);
  *(short8v*)(dst + lane * 8) = o;

  if (isFace) {
    float fs = f0.x + f0.y + f0.z + f0.w + f1.x + f1.y + f1.z + f1.w;
#pragma unroll
    for (int off = 1; off < 64; off <<= 1) fs += __shfl_xor(fs, off);
    if (lane == 0) mask[row] = (fs != 0.0f) ? 1.0f : 0.0f;
  }
}

// ---------------------------------------------------------------------------
// Ring GEMM: 128x128 tile, BK=32, 4 waves (2x2), wave-tile 64x64.
// LDS ring of 3 x (A 8KB + B 8KB) = 48 KB. Buffer i at i*8192 shorts:
// A rows [0,4096), B [4096,8192); row r at r*32 shorts, 4 slots x 8 bf16;
// slot s of row r holds global k-slot s ^ ((r>>1)&3) [r2-measured 0-conflict].
// Per K-tile: STAGE(t+2) -> 8 ds_read_b128 + 16 MFMA -> vmcnt(4) -> s_barrier.
// ---------------------------------------------------------------------------
#define MFMA(A_, B_, C_) __builtin_amdgcn_mfma_f32_16x16x32_bf16(A_, B_, C_, 0, 0, 0)

#define GLDS(SRC, DSTOFF)                                                     \
  __builtin_amdgcn_global_load_lds(                                           \
      (const __attribute__((address_space(1))) void*)(SRC),                   \
      (__attribute__((address_space(3))) void*)(lds + (DSTOFF)), 16, 0, 0)

__global__ __launch_bounds__(256) void grl_gemm_ring(
    const unsigned short* __restrict__ A, const unsigned short* __restrict__ Bn,
    float* __restrict__ S_all, float* __restrict__ pos,
    float* __restrict__ diagm) {
  __shared__ __align__(16) unsigned short lds[3 * 8192];  // 48 KB

  const int tid = threadIdx.x;
  const int lane = tid & 63;
  const int wid = tid >> 6;
  const int wr = wid >> 1;   // 0..1 (M)
  const int wc = wid & 1;    // 0..1 (N)
  const int bx = blockIdx.x;
  const int by = blockIdx.y;
  const int m0 = bx * 128;
  const int n0 = by * 128;

  // ---- stager: 4 gload_lds per K-tile per thread ------------------------
  // instr covers 64 rows: row = base + wid*16 + (lane>>2), slot = lane&3;
  // source k-slot g = (lane&3) ^ ((row>>1)&3) = (lane&3) ^ ((lane>>3)&3).
  const int g = (lane & 3) ^ ((lane >> 3) & 3);
  const int sr = wid * 16 + (lane >> 2);   // 0..63
  const unsigned short* gA = A + (size_t)(m0 + sr) * DIM_D + g * 8;
  const unsigned short* gB = Bn + (size_t)(n0 + sr) * DIM_D + g * 8;
  const int lb0 = wid * 512;  // wave-uniform LDS base (shorts)

#define STAGE(T)                                            \
  do {                                                      \
    const int bo_ = ((T) % 3) * 8192;                       \
    GLDS(gA + (T) * 32, bo_ + lb0);                         \
    GLDS(gA + (T) * 32 + 64 * DIM_D, bo_ + 2048 + lb0);     \
    GLDS(gB + (T) * 32, bo_ + 4096 + lb0);                  \
    GLDS(gB + (T) * 32 + 64 * DIM_D, bo_ + 6144 + lb0);     \
  } while (0)

  // ---- reader: frag row = base + (lane&15), k-slot = lane>>4, swizzled --
  const int fo = (lane & 15) * 32 + (((lane >> 4) ^ ((lane >> 1) & 3)) * 8);

  f32x4 acc[4][4];
#pragma unroll
  for (int i = 0; i < 4; ++i)
#pragma unroll
    for (int j = 0; j < 4; ++j) acc[i][j] = (f32x4){0.f, 0.f, 0.f, 0.f};

#define KBODY(T)                                                          \
  do {                                                                    \
    const unsigned short* Lb = lds + ((T) % 3) * 8192;                    \
    short8v a0 = *(const short8v*)(Lb + (wr * 64 + 0) * 32 + fo);         \
    short8v a1 = *(const short8v*)(Lb + (wr * 64 + 16) * 32 + fo);        \
    short8v a2 = *(const short8v*)(Lb + (wr * 64 + 32) * 32 + fo);        \
    short8v a3 = *(const short8v*)(Lb + (wr * 64 + 48) * 32 + fo);        \
    short8v b0 = *(const short8v*)(Lb + 4096 + (wc * 64 + 0) * 32 + fo);  \
    short8v b1 = *(const short8v*)(Lb + 4096 + (wc * 64 + 16) * 32 + fo); \
    short8v b2 = *(const short8v*)(Lb + 4096 + (wc * 64 + 32) * 32 + fo); \
    short8v b3 = *(const short8v*)(Lb + 4096 + (wc * 64 + 48) * 32 + fo); \
    acc[0][0] = MFMA(a0, b0, acc[0][0]);                                  \
    acc[0][1] = MFMA(a0, b1, acc[0][1]);                                  \
    acc[0][2] = MFMA(a0, b2, acc[0][2]);                                  \
    acc[0][3] = MFMA(a0, b3, acc[0][3]);                                  \
    acc[1][0] = MFMA(a1, b0, acc[1][0]);                                  \
    acc[1][1] = MFMA(a1, b1, acc[1][1]);                                  \
    acc[1][2] = MFMA(a1, b2, acc[1][2]);                                  \
    acc[1][3] = MFMA(a1, b3, acc[1][3]);                                  \
    acc[2][0] = MFMA(a2, b0, acc[2][0]);                                  \
    acc[2][1] = MFMA(a2, b1, acc[2][1]);                                  \
    acc[2][2] = MFMA(a2, b2, acc[2][2]);                                  \
    acc[2][3] = MFMA(a2, b3, acc[2][3]);                                  \
    acc[3][0] = MFMA(a3, b0, acc[3][0]);                                  \
    acc[3][1] = MFMA(a3, b1, acc[3][1]);                                  \
    acc[3][2] = MFMA(a3, b2, acc[3][2]);                                  \
    acc[3][3] = MFMA(a3, b3, acc[3][3]);                                  \
  } while (0)

  // ---- prologue: stage tiles 0,1 (8 loads); wait tile 0 (counted) -------
  STAGE(0);
  STAGE(1);
  asm volatile("s_waitcnt vmcnt(4)" ::: "memory");
  __builtin_amdgcn_s_barrier();

  // ---- main loop: stage t+2, compute t; vmcnt(4) keeps t+2 in flight ----
  for (int t = 0; t < 14; ++t) {
    STAGE(t + 2);
    KBODY(t);
    asm volatile("s_waitcnt vmcnt(4)" ::: "memory");  // tile t+1 landed
    __builtin_amdgcn_s_barrier();
  }
  // ---- tail -------------------------------------------------------------
  KBODY(14);
  asm volatile("s_waitcnt vmcnt(0)" ::: "memory");    // tile 15 landed
  __builtin_amdgcn_s_barrier();
  KBODY(15);

  // ---- fused epilogue: relu, ==1->0, row sums (r15-identical) -----------
  // C/D layout (m89-verified): col = lane&15 (n), row = (lane>>4)*4 + reg
  float rsum[4][4];
#pragma unroll
  for (int mi = 0; mi < 4; ++mi)
#pragma unroll
    for (int r = 0; r < 4; ++r) rsum[mi][r] = 0.0f;
#pragma unroll
  for (int mi = 0; mi < 4; ++mi)
#pragma unroll
    for (int ni = 0; ni < 4; ++ni)
#pragma unroll
      for (int r = 0; r < 4; ++r) {
        float v = acc[mi][ni][r];
        v = v > 0.0f ? v : 0.0f;
        v = (v == 1.0f) ? 0.0f : v;
        rsum[mi][r] += v;
      }
#pragma unroll
  for (int mi = 0; mi < 4; ++mi)
#pragma unroll
    for (int r = 0; r < 4; ++r) {
      float s = rsum[mi][r];
      s += __shfl_xor(s, 1);
      s += __shfl_xor(s, 2);
      s += __shfl_xor(s, 4);
      s += __shfl_xor(s, 8);
      if ((lane & 15) == 0)
        atomicAdd(&S_all[m0 + wr * 64 + mi * 16 + (lane >> 4) * 4 + r], s);
    }

  // ---- fused diagonal (blocks with by == bx>>1 only; r15-identical) -----
  if (by == (bx >> 1)) {
#pragma unroll
    for (int mi = 0; mi < 4; ++mi) {
      const int R0 = m0 + wr * 64 + mi * 16;  // rows R0..R0+15 share b_
      const int tc = ((R0 >> 5) << 4) - n0;   // diag col offset in tile
      if ((tc >> 6) == wc) {
        const int dn = (tc >> 4) & 3;
#pragma unroll
        for (int ni = 0; ni < 4; ++ni)
          if (ni == dn) {
#pragma unroll
            for (int r = 0; r < 4; ++r) {
              float v = acc[mi][ni][r];
              v = v > 0.0f ? v : 0.0f;
              float vm = (v == 1.0f) ? 0.0f : v;
              float ps = v, ds = vm;
              ps += __shfl_xor(ps, 1); ds += __shfl_xor(ds, 1);
              ps += __shfl_xor(ps, 2); ds += __shfl_xor(ds, 2);
              ps += __shfl_xor(ps, 4); ds += __shfl_xor(ds, 4);
              ps += __shfl_xor(ps, 8); ds += __shfl_xor(ds, 8);
              if ((lane & 15) == 0) {
                const int R = R0 + (lane >> 4) * 4 + r;
                pos[R] = ps;
                diagm[R] = ds;
              }
            }
          }
      }
    }
  }
}

// ---------------------------------------------------------------------------
// Finalize: rank + global sum. Single block, 1024 threads.
// ---------------------------------------------------------------------------
__global__ __launch_bounds__(1024) void grl_final(
    const float* __restrict__ S_all, const float* __restrict__ diagm,
    const float* __restrict__ pos, const float* __restrict__ mask,
    float* __restrict__ out) {
  __shared__ float red[16];
  const int lane = threadIdx.x & 63;
  const int wv = threadIdx.x >> 6;
  float s = 0.0f;
  for (int r = threadIdx.x; r < M_TOT; r += 1024) {
    const float neg = (S_all[r] - diagm[r]) / 255.0f;  // 255 + 1e-8 == 255.0f
    float rank = neg - pos[r] + 0.2f;
    rank = rank > 0.0f ? rank : 0.0f;
    s += rank * mask[r];
  }
#pragma unroll
  for (int off = 1; off < 64; off <<= 1) s += __shfl_xor(s, off);
  if (lane == 0) red[wv] = s;
  __syncthreads();
  if (threadIdx.x == 0) {
    float t = 0.0f;
#pragma unroll
    for (int i = 0; i < 16; ++i) t += red[i];
    out[0] = t / 256.0f;  // BETA * sum / B
  }
}

// ---------------------------------------------------------------------------
extern "C" void kernel_launch(void* const* d_in, const int* in_sizes, int n_in,
                              void* d_out, int out_size, void* d_ws, size_t ws_size,
                              hipStream_t stream) {
  const float* face = (const float*)d_in[0];
  const float* ner = (const float*)d_in[1];

  unsigned short* face_bf = (unsigned short*)d_ws;
  unsigned short* ner_bf = face_bf + (size_t)M_TOT * DIM_D;
  float* S_all = (float*)(ner_bf + (size_t)N_TOT * DIM_D);
  float* diagm = S_all + M_TOT;
  float* pos = diagm + M_TOT;
  float* mask = pos + M_TOT;

  cvt_all<<<(M_TOT + N_TOT) / 4, 256, 0, stream>>>(face, ner, face_bf, ner_bf,
                                                   mask, S_all);
  grl_gemm_ring<<<dim3(M_TOT / 128, N_TOT / 128), 256, 0, stream>>>(
      face_bf, ner_bf, S_all, pos, diagm);
  grl_final<<<1, 1024, 0, stream>>>(S_all, diagm, pos, mask, (float*)d_out);
}